// Round 2
// baseline (1019.274 us; speedup 1.0000x reference)
//
#include <hip/hip_runtime.h>

// NLinear: out[b,n,o] = sum_i x[b,n,i] * w[n,i,o] + bias[n,o]
// B=4096, N=200, D=64.  Pure fp32.
//
// R1 post-mortem: LDS-broadcast inner loop saturated the per-CU LDS pipe
// (16 ds_read_b128/row ~= 256 us of LDS time vs 42.7 us VALU floor).
// R2: x rows are wave-uniform -> load them through the SCALAR path
// (s_load_dwordx16 into SGPRs via readfirstlane-uniform pointer), inner loop
// v_fmac_f32 v_acc, s_x, v_w.  No LDS, no barriers.

#define B_DIM 4096
#define N_DIM 200
#define D 64
#define ROWS_PER_WAVE 64
#define ROWS_PER_BLOCK 256   // 4 waves/block

typedef __attribute__((ext_vector_type(16))) float f32x16;

__device__ __forceinline__ const float* uniform_ptr(const float* p) {
    uint64_t v = (uint64_t)(uintptr_t)p;
    uint32_t lo = __builtin_amdgcn_readfirstlane((uint32_t)v);
    uint32_t hi = __builtin_amdgcn_readfirstlane((uint32_t)(v >> 32));
    return (const float*)(uintptr_t)(((uint64_t)hi << 32) | lo);
}

__global__ __launch_bounds__(256, 4)
void nlinear_kernel(const float* __restrict__ x,
                    const float* __restrict__ w,
                    const float* __restrict__ bias,
                    float* __restrict__ out) {
    const int n    = blockIdx.y;
    const int tid  = threadIdx.x;
    const int lane = tid & 63;
    // wave index forced into an SGPR so all x-row addresses are uniform
    const int wave = __builtin_amdgcn_readfirstlane(tid >> 6);
    const int b0   = blockIdx.x * ROWS_PER_BLOCK + wave * ROWS_PER_WAVE;

    // Lane `lane` holds weight column w[n][:,lane] in 64 VGPRs.
    // Coalesced loads; 16 KB/ n, shared by 16 blocks -> L1/L2-hot.
    const float* wn = w + (size_t)n * (D * D);
    float wreg[D];
#pragma unroll
    for (int i = 0; i < D; ++i) wreg[i] = wn[i * D + lane];

    const float bv = bias[n * D + lane];

    const size_t row_stride = (size_t)N_DIM * D;   // 12800 floats
    const float* xrow = uniform_ptr(x + (size_t)b0 * row_stride + (size_t)n * D);
    float*       orow = out + (size_t)b0 * row_stride + (size_t)n * D + lane;

    for (int r = 0; r < ROWS_PER_WAVE; ++r) {
        // Wave-uniform address -> s_load_dwordx16 x4 (x row into SGPRs).
        const f32x16* xv = (const f32x16*)xrow;
        const f32x16 c0 = xv[0];
        const f32x16 c1 = xv[1];
        const f32x16 c2 = xv[2];
        const f32x16 c3 = xv[3];

        // 4 independent accumulator chains; fmac reads 1 SGPR + 1 VGPR.
        float a0 = bv, a1 = 0.f, a2 = 0.f, a3 = 0.f;
#pragma unroll
        for (int j = 0; j < 16; ++j) {
            a0 = fmaf(c0[j], wreg[j],      a0);
            a1 = fmaf(c1[j], wreg[16 + j], a1);
            a2 = fmaf(c2[j], wreg[32 + j], a2);
            a3 = fmaf(c3[j], wreg[48 + j], a3);
        }
        *orow = (a0 + a1) + (a2 + a3);   // coalesced 256B store per wave

        xrow += row_stride;
        orow += row_stride;
    }
}

extern "C" void kernel_launch(void* const* d_in, const int* in_sizes, int n_in,
                              void* d_out, int out_size, void* d_ws, size_t ws_size,
                              hipStream_t stream) {
    const float* x    = (const float*)d_in[0];   // (4096, 200, 64)
    const float* w    = (const float*)d_in[1];   // (1, 200, 64, 64)
    const float* bias = (const float*)d_in[2];   // (1, 200, 64)
    float*       out  = (float*)d_out;           // (4096, 200, 64)

    dim3 grid(B_DIM / ROWS_PER_BLOCK, N_DIM);    // 16 x 200 = 3200 blocks
    nlinear_kernel<<<grid, dim3(256), 0, stream>>>(x, w, bias, out);
}